// Round 6
// baseline (254.135 us; speedup 1.0000x reference)
//
#include <hip/hip_runtime.h>
#include <math.h>

#define NN 50000
#define NE 1000000
#define EC 16            // edge chunks, chunk = e >> CSH
#define CSH 16           // chunk size 65536
#define WR 8             // counter ranges
#define RNG 6250         // counters per range (8*6250 = NN)
#define RPAD 6272        // padded dump stride (25088B = 196 lines, block-exclusive)
#define NCNT (EC * WR)   // 128 count blocks
#define NGB 782          // gemm L1 blocks: ceil(NN/64)
#define TOTB (NCNT + NGB)

typedef __bf16 bf16x8 __attribute__((ext_vector_type(8)));
typedef float f32x4 __attribute__((ext_vector_type(4)));

__device__ inline unsigned short f2bf(float f) {          // fp32 -> bf16 RNE
    unsigned u = __float_as_uint(f);
    u += 0x7FFFu + ((u >> 16) & 1u);
    return (unsigned short)(u >> 16);
}
__device__ inline float bf2f(unsigned short s) {
    return __uint_as_float(((unsigned)s) << 16);
}
__device__ inline float bflo(unsigned r) { return __uint_as_float(r << 16); }
__device__ inline float bfhi(unsigned r) { return __uint_as_float(r & 0xffff0000u); }

// ---- prep: W1->Bt1[64][320] bf16 pad, W2->Bt2[64][64] bf16 ----
// (cnt zeroing dropped: chunked-histogram count fully overwrites its regions)
__global__ __launch_bounds__(256) void prep_init(const float* __restrict__ W1,
        const float* __restrict__ W2, unsigned short* __restrict__ Bt1,
        unsigned short* __restrict__ Bt2)
{
    int t = blockIdx.x * 256 + threadIdx.x;        // 96*256 = 24576 = 64*320+64*64
    if (t < 64 * 320) {
        int c = t / 320, k = t % 320;
        Bt1[t] = (k < 300) ? f2bf(W1[k * 64 + c]) : (unsigned short)0;
    } else {
        int i = t - 64 * 320;
        int c = i >> 6, k = i & 63;
        Bt2[i] = f2bf(W2[k * 64 + c]);
    }
}

// ---- FAT kernel: blocks [0,NCNT) = atomic-FREE CSR count, rest = L1 GEMM.
//      R0-R4 showed global atomicAdd is a memory-side RMW wall (~25G/s,
//      32B write-through per op) that is ADDITIVE with any concurrent
//      traffic -- scope/padding/replicas/interleaving all no-ops. Fix:
//      remove global atomics. Block (c,w) scans edge chunk c (65536 edges,
//      e>>16==c) and histograms dst in range [w*6250,(w+1)*6250) via LDS
//      fetch-add; rank byte -> pos[e]; counts -> exclusive cnt region.
//      Count is now pure reads+LDS and overlaps the co-resident GEMM. ----
__global__ __launch_bounds__(256) void k1_count_gemm(
        const int* __restrict__ ei, int* __restrict__ cnt,
        unsigned char* __restrict__ pos,
        const float* __restrict__ A, const unsigned short* __restrict__ Bt,
        unsigned short* __restrict__ hb,
        const float* __restrict__ asrc, const float* __restrict__ adst,
        float* __restrict__ ss, float* __restrict__ sd)
{
    __shared__ __align__(16) int sm[RNG];          // 25000B; gemm aliases 10240B
    const int tid = threadIdx.x;
    const int bid = blockIdx.x;

    if (bid < NCNT) {
        // ---------------- count body: chunk c, range w ----------------
        const int c = bid >> 3, w = bid & 7;
        const int lo = w * RNG;
        for (int j = tid; j < RNG; j += 256) sm[j] = 0;
        __syncthreads();
        const int base = c << CSH;
        for (int it = 0; it < (1 << CSH) / 1024; ++it) {
            int e = base + (it * 256 + tid) * 4;
            if (e < NE) {                           // NE%4==0 -> whole int4 valid
                int4 d = *(const int4*)(ei + NE + e);
                unsigned t0 = (unsigned)(d.x - lo), t1 = (unsigned)(d.y - lo);
                unsigned t2 = (unsigned)(d.z - lo), t3 = (unsigned)(d.w - lo);
                if (t0 < RNG) pos[e]     = (unsigned char)atomicAdd(&sm[t0], 1);
                if (t1 < RNG) pos[e + 1] = (unsigned char)atomicAdd(&sm[t1], 1);
                if (t2 < RNG) pos[e + 2] = (unsigned char)atomicAdd(&sm[t2], 1);
                if (t3 < RNG) pos[e + 3] = (unsigned char)atomicAdd(&sm[t3], 1);
            }
        }
        __syncthreads();
        int* dstp = cnt + (size_t)bid * RPAD;      // exclusive 25088B region
        for (int j = tid; j < RNG; j += 256) dstp[j] = sm[j];
        return;
    }

    // ---------------- gemm body (HEADS=8, A fp32, K=300, KT=10) ----------------
    unsigned short* lds = (unsigned short*)sm;
    const int row0 = (bid - NCNT) * 64;
    const int lane = tid & 63, w = tid >> 6;
    const int quad = lane >> 4, mm = lane & 15;
    const int sr = tid >> 2, q8 = (tid & 3) * 8;
    const int gsr = row0 + sr;
    const int K = 300, KT = 10, Kpad = 320, M = NN;

    f32x4 acc[4];
    #pragma unroll
    for (int i = 0; i < 4; ++i) acc[i] = (f32x4){0.f, 0.f, 0.f, 0.f};

    for (int kt = 0; kt < KT; ++kt) {
        const int k0 = kt * 32;
        int4 apack = {0, 0, 0, 0};
        if (gsr < M) {
            const float* ap = A + (size_t)gsr * K + k0 + q8;
            unsigned short* up = (unsigned short*)&apack;
            if (k0 + q8 + 7 < K) {
                float4 v0 = *(const float4*)ap;
                float4 v1 = *(const float4*)(ap + 4);
                up[0]=f2bf(v0.x); up[1]=f2bf(v0.y); up[2]=f2bf(v0.z); up[3]=f2bf(v0.w);
                up[4]=f2bf(v1.x); up[5]=f2bf(v1.y); up[6]=f2bf(v1.z); up[7]=f2bf(v1.w);
            } else {
                #pragma unroll
                for (int j = 0; j < 8; ++j)
                    up[j] = (k0 + q8 + j < K) ? f2bf(ap[j]) : (unsigned short)0;
            }
        }
        *(int4*)(lds + sr * 40 + q8) = apack;
        *(int4*)(lds + 2560 + sr * 40 + q8) =
            *(const int4*)(Bt + (size_t)sr * Kpad + k0 + q8);
        __syncthreads();
        bf16x8 af = *(const bf16x8*)(lds + (w * 16 + mm) * 40 + quad * 8);
        #pragma unroll
        for (int nt = 0; nt < 4; ++nt) {
            bf16x8 bfv = *(const bf16x8*)(lds + 2560 + (nt * 16 + mm) * 40 + quad * 8);
            acc[nt] = __builtin_amdgcn_mfma_f32_16x16x32_bf16(af, bfv, acc[nt], 0, 0, 0);
        }
        __syncthreads();
    }
    // epilogue: C (col=lane&15, row=quad*4+reg) -> LDS bf16 tile
    #pragma unroll
    for (int nt = 0; nt < 4; ++nt)
        #pragma unroll
        for (int reg = 0; reg < 4; ++reg)
            lds[w * 1152 + (quad * 4 + reg) * 72 + nt * 16 + mm] = f2bf(acc[nt][reg]);
    __syncthreads();
    const int cg = (tid & 3) * 16;
    const unsigned short* crow = lds + (sr >> 4) * 1152 + (sr & 15) * 72;
    if (gsr < M) {
        *(int4*)(hb + (size_t)gsr * 64 + cg)     = *(const int4*)(crow + cg);
        *(int4*)(hb + (size_t)gsr * 64 + cg + 8) = *(const int4*)(crow + cg + 8);
    }
    #pragma unroll
    for (int hh = 0; hh < 2; ++hh) {
        int hd = (tid & 3) + hh * 4;
        float pss = 0.f, psd = 0.f;
        #pragma unroll
        for (int c = 0; c < 8; ++c) {
            float hv = bf2f(crow[hd * 8 + c]);
            pss += hv * asrc[hd * 8 + c];
            psd += hv * adst[hd * 8 + c];
        }
        if (gsr < M) { ss[gsr * 8 + hd] = pss; sd[gsr * 8 + hd] = psd; }
    }
}

// ---- MFMA GEMM for layer 2 (A bf16, HEADS=1, K=64, KT=2), fused h+logits ----
__global__ __launch_bounds__(256) void gemm_l2(const unsigned short* __restrict__ A,
        const unsigned short* __restrict__ Bt, unsigned short* __restrict__ hb,
        const float* __restrict__ asrc, const float* __restrict__ adst,
        float* __restrict__ ss, float* __restrict__ sd)
{
    __shared__ unsigned short lds[5120];
    const int tid  = threadIdx.x;
    const int row0 = blockIdx.x * 64;
    const int lane = tid & 63, w = tid >> 6;
    const int quad = lane >> 4, mm = lane & 15;
    const int sr = tid >> 2, q8 = (tid & 3) * 8;
    const int gsr = row0 + sr;
    const int K = 64, KT = 2, Kpad = 64, M = NN;

    f32x4 acc[4];
    #pragma unroll
    for (int i = 0; i < 4; ++i) acc[i] = (f32x4){0.f, 0.f, 0.f, 0.f};

    for (int kt = 0; kt < KT; ++kt) {
        const int k0 = kt * 32;
        int4 apack = {0, 0, 0, 0};
        if (gsr < M) apack = *(const int4*)(A + (size_t)gsr * K + k0 + q8);
        *(int4*)(lds + sr * 40 + q8) = apack;
        *(int4*)(lds + 2560 + sr * 40 + q8) =
            *(const int4*)(Bt + (size_t)sr * Kpad + k0 + q8);
        __syncthreads();
        bf16x8 af = *(const bf16x8*)(lds + (w * 16 + mm) * 40 + quad * 8);
        #pragma unroll
        for (int nt = 0; nt < 4; ++nt) {
            bf16x8 bfv = *(const bf16x8*)(lds + 2560 + (nt * 16 + mm) * 40 + quad * 8);
            acc[nt] = __builtin_amdgcn_mfma_f32_16x16x32_bf16(af, bfv, acc[nt], 0, 0, 0);
        }
        __syncthreads();
    }
    #pragma unroll
    for (int nt = 0; nt < 4; ++nt)
        #pragma unroll
        for (int reg = 0; reg < 4; ++reg)
            lds[w * 1152 + (quad * 4 + reg) * 72 + nt * 16 + mm] = f2bf(acc[nt][reg]);
    __syncthreads();
    const int cg = (tid & 3) * 16;
    const unsigned short* crow = lds + (sr >> 4) * 1152 + (sr & 15) * 72;
    if (gsr < M) {
        *(int4*)(hb + (size_t)gsr * 64 + cg)     = *(const int4*)(crow + cg);
        *(int4*)(hb + (size_t)gsr * 64 + cg + 8) = *(const int4*)(crow + cg + 8);
    }
    int p = tid & 3;
    float pss = 0.f, psd = 0.f;
    #pragma unroll
    for (int c = 0; c < 16; ++c) {
        float hv = bf2f(crow[p * 16 + c]);
        pss += hv * asrc[p * 16 + c];
        psd += hv * adst[p * 16 + c];
    }
    pss += __shfl_xor(pss, 1); psd += __shfl_xor(psd, 1);
    pss += __shfl_xor(pss, 2); psd += __shfl_xor(psd, 2);
    if (p == 0 && gsr < M) { ss[gsr] = pss; sd[gsr] = psd; }
}

// ---- scan stage 1: per-node total over 16 chunks; emit chunk prefixes ----
__global__ __launch_bounds__(1024) void scan1(const int* __restrict__ cnt,
        int* __restrict__ excl, int* __restrict__ sums, int* __restrict__ rpre)
{
    __shared__ int buf[1024];
    int tid = threadIdx.x;
    int i = blockIdx.x * 1024 + tid;
    int v = 0;
    if (i < NN) {
        int w = i / RNG;                    // counter range 0..7
        int j = i - w * RNG;
        int run = 0;
        int pre[EC];
        #pragma unroll
        for (int c = 0; c < EC; ++c) {
            pre[c] = run;
            run += cnt[(size_t)(c * 8 + w) * RPAD + j];
        }
        v = run;
        #pragma unroll
        for (int q = 0; q < EC / 4; ++q)
            *(int4*)(rpre + (size_t)i * EC + q * 4) =
                make_int4(pre[q * 4], pre[q * 4 + 1], pre[q * 4 + 2], pre[q * 4 + 3]);
    }
    buf[tid] = v;
    __syncthreads();
    #pragma unroll
    for (int off = 1; off < 1024; off <<= 1) {
        int t = (tid >= off) ? buf[tid - off] : 0;
        __syncthreads();
        buf[tid] += t;
        __syncthreads();
    }
    if (i < NN) excl[i] = buf[tid] - v;
    if (tid == 1023) sums[blockIdx.x] = buf[1023];
}

// ------------- scan stage 2+3 merged: each block scans 49 sums redundantly -------------
__global__ __launch_bounds__(1024) void scan23(const int* __restrict__ excl,
        const int* __restrict__ sums, int* __restrict__ rowptr)
{
    int off = 0;
    for (int j = 0; j < (int)blockIdx.x; ++j) off += sums[j];   // uniform scalar loop
    int i = blockIdx.x * 1024 + threadIdx.x;
    if (i < NN) rowptr[i] = excl[i] + off;
    if (i == 0) rowptr[NN] = NE;
}

// ------ CSR scatter: slot = rowptr[d] + rpre[d][chunk(e)] + pos[e] ------
__global__ __launch_bounds__(256) void scatter_k(const int* __restrict__ ei,
        const int* __restrict__ rowptr, const unsigned char* __restrict__ pos,
        const int* __restrict__ rpre, unsigned short* __restrict__ col)
{
    int e = (blockIdx.x * 256 + threadIdx.x) * 4;   // NE % 4 == 0
    if (e >= NE) return;
    int c = e >> CSH;                               // chunk uniform over the int4
    int4 s = *(const int4*)(ei + e);
    int4 d = *(const int4*)(ei + NE + e);
    uchar4 p = *(const uchar4*)(pos + e);
    int r0 = rowptr[d.x] + rpre[(d.x << 4) + c] + p.x;
    int r1 = rowptr[d.y] + rpre[(d.y << 4) + c] + p.y;
    int r2 = rowptr[d.z] + rpre[(d.z << 4) + c] + p.z;
    int r3 = rowptr[d.w] + rpre[(d.w << 4) + c] + p.w;
    col[r0] = (unsigned short)s.x;
    col[r1] = (unsigned short)s.y;
    col[r2] = (unsigned short)s.z;
    col[r3] = (unsigned short)s.w;
}

#define LEAKY(s) ((s) > 0.f ? (s) : 0.2f * (s))

// ------- layer1 agg: wave/node, 16 edges in flight (4 slots x 4-deep batch) -------
__global__ __launch_bounds__(256) void agg_l1(const int* __restrict__ rowptr,
        const unsigned short* __restrict__ col, const unsigned short* __restrict__ hb,
        const float* __restrict__ ss, const float* __restrict__ sd,
        const float* __restrict__ b, unsigned short* __restrict__ out)
{
    int n = (blockIdx.x * 256 + threadIdx.x) >> 6;
    int lane = threadIdx.x & 63;
    if (n >= NN) return;
    const int es = lane >> 4;            // edge slot 0..3
    const int cg = (lane & 15) << 2;     // channel group base
    const int hd = cg >> 3;              // head
    float sdst = sd[n * 8 + hd];
    int r0 = rowptr[n], r1 = rowptr[n + 1];
    f32x4 acc = {0.f, 0.f, 0.f, 0.f};
    float dsum = 0.f;
    for (int i = r0; i < r1; i += 16) {
        int av[4]; bool vv[4];
        #pragma unroll
        for (int u = 0; u < 4; ++u) {
            int e = i + u * 4 + es;
            vv[u] = e < r1;
            av[u] = (int)col[vv[u] ? e : r0];
        }
        uint2 rr[4]; float sv[4];
        #pragma unroll
        for (int u = 0; u < 4; ++u) {
            rr[u] = *(const uint2*)(hb + av[u] * 64 + cg);
            sv[u] = ss[av[u] * 8 + hd];
        }
        #pragma unroll
        for (int u = 0; u < 4; ++u) {
            float wv = vv[u] ? __expf(LEAKY(sv[u] + sdst)) : 0.f;
            acc[0] += wv * bflo(rr[u].x);
            acc[1] += wv * bfhi(rr[u].x);
            acc[2] += wv * bflo(rr[u].y);
            acc[3] += wv * bfhi(rr[u].y);
            dsum += wv;
        }
    }
    #pragma unroll
    for (int m = 16; m <= 32; m <<= 1) {
        acc[0] += __shfl_xor(acc[0], m); acc[1] += __shfl_xor(acc[1], m);
        acc[2] += __shfl_xor(acc[2], m); acc[3] += __shfl_xor(acc[3], m);
        dsum += __shfl_xor(dsum, m);
    }
    if (es == 0) {
        float inv = 1.f / (dsum + 1e-16f);
        // ELU via __expf-1: output is bf16, so exp-1 absolute error (~1e-7) is invisible
        float v0 = acc[0] * inv + b[cg + 0]; v0 = v0 > 0.f ? v0 : __expf(v0) - 1.f;
        float v1 = acc[1] * inv + b[cg + 1]; v1 = v1 > 0.f ? v1 : __expf(v1) - 1.f;
        float v2 = acc[2] * inv + b[cg + 2]; v2 = v2 > 0.f ? v2 : __expf(v2) - 1.f;
        float v3 = acc[3] * inv + b[cg + 3]; v3 = v3 > 0.f ? v3 : __expf(v3) - 1.f;
        unsigned o01 = (unsigned)f2bf(v0) | ((unsigned)f2bf(v1) << 16);
        unsigned o23 = (unsigned)f2bf(v2) | ((unsigned)f2bf(v3) << 16);
        *(uint2*)(out + n * 64 + cg) = make_uint2(o01, o23);
    }
}

// ------- layer2 agg: wave/node, 16 edges in flight, fp32 out -------
__global__ __launch_bounds__(256) void agg_l2(const int* __restrict__ rowptr,
        const unsigned short* __restrict__ col, const unsigned short* __restrict__ hb,
        const float* __restrict__ ss, const float* __restrict__ sd,
        const float* __restrict__ b, float* __restrict__ out)
{
    int n = (blockIdx.x * 256 + threadIdx.x) >> 6;
    int lane = threadIdx.x & 63;
    if (n >= NN) return;
    const int es = lane >> 4;
    const int cg = (lane & 15) << 2;
    float sdst = sd[n];
    int r0 = rowptr[n], r1 = rowptr[n + 1];
    f32x4 acc = {0.f, 0.f, 0.f, 0.f};
    float dsum = 0.f;
    for (int i = r0; i < r1; i += 16) {
        int av[4]; bool vv[4];
        #pragma unroll
        for (int u = 0; u < 4; ++u) {
            int e = i + u * 4 + es;
            vv[u] = e < r1;
            av[u] = (int)col[vv[u] ? e : r0];
        }
        uint2 rr[4]; float sv[4];
        #pragma unroll
        for (int u = 0; u < 4; ++u) {
            rr[u] = *(const uint2*)(hb + av[u] * 64 + cg);
            sv[u] = ss[av[u]];
        }
        #pragma unroll
        for (int u = 0; u < 4; ++u) {
            float wv = vv[u] ? __expf(LEAKY(sv[u] + sdst)) : 0.f;
            acc[0] += wv * bflo(rr[u].x);
            acc[1] += wv * bfhi(rr[u].x);
            acc[2] += wv * bflo(rr[u].y);
            acc[3] += wv * bfhi(rr[u].y);
            dsum += wv;
        }
    }
    #pragma unroll
    for (int m = 16; m <= 32; m <<= 1) {
        acc[0] += __shfl_xor(acc[0], m); acc[1] += __shfl_xor(acc[1], m);
        acc[2] += __shfl_xor(acc[2], m); acc[3] += __shfl_xor(acc[3], m);
        dsum += __shfl_xor(dsum, m);
    }
    if (es == 0) {
        float inv = 1.f / (dsum + 1e-16f);
        float4 o;
        o.x = acc[0] * inv + b[cg + 0];
        o.y = acc[1] * inv + b[cg + 1];
        o.z = acc[2] * inv + b[cg + 2];
        o.w = acc[3] * inv + b[cg + 3];
        *(float4*)(out + n * 64 + cg) = o;
    }
}

extern "C" void kernel_launch(void* const* d_in, const int* in_sizes, int n_in,
                              void* d_out, int out_size, void* d_ws, size_t ws_size,
                              hipStream_t stream)
{
    const float* x      = (const float*)d_in[0];
    const int*   ei     = (const int*)d_in[1];
    const float* W1     = (const float*)d_in[2];
    const float* a_src1 = (const float*)d_in[3];
    const float* a_dst1 = (const float*)d_in[4];
    const float* b1     = (const float*)d_in[5];
    const float* W2     = (const float*)d_in[6];
    const float* a_src2 = (const float*)d_in[7];
    const float* a_dst2 = (const float*)d_in[8];
    const float* b2     = (const float*)d_in[9];
    float* out = (float*)d_out;

    // workspace (16B-aligned blocks first)
    char* wp = (char*)d_ws;
    unsigned short* hb  = (unsigned short*)wp;  wp += (size_t)NN * 64 * 2;  // h1 then h2 (bf16)
    unsigned short* P1b = (unsigned short*)wp;  wp += (size_t)NN * 64 * 2;  // h2in (bf16)
    unsigned short* Bt1 = (unsigned short*)wp;  wp += (size_t)64 * 320 * 2; // W1^T bf16 padded
    unsigned short* Bt2 = (unsigned short*)wp;  wp += (size_t)64 * 64 * 2;  // W2^T bf16
    float* ss1 = (float*)wp;  wp += (size_t)NN * 8 * 4;
    float* sd1 = (float*)wp;  wp += (size_t)NN * 8 * 4;
    int* cnt    = (int*)wp;  wp += (size_t)NCNT * RPAD * 4;  // per-(chunk,range) counts
    int* rpre   = (int*)wp;  wp += (size_t)NN * EC * 4;      // per-node chunk prefixes
    int* excl   = (int*)wp;  wp += (size_t)NN * 4;
    int* sums   = (int*)wp;  wp += 64 * 4;
    int* rowptr = (int*)wp;  wp += (size_t)(NN + 4) * 4;
    unsigned short* col = (unsigned short*)wp;  wp += (size_t)(NE + 8) * 2;
    unsigned char*  pos = (unsigned char*)wp;   wp += (size_t)NE;
    float* ss2 = ss1;                    // alias (layer1 logits dead in layer2)
    float* sd2 = ss1 + NN;

    const int NB = (NN + 1023) / 1024;   // 49

    prep_init<<<96, 256, 0, stream>>>(W1, W2, Bt1, Bt2);
    // FAT: atomic-free chunked count (blocks 0..127) + L1 GEMM (128..909)
    k1_count_gemm<<<TOTB, 256, 0, stream>>>(
        ei, cnt, pos, x, Bt1, hb, a_src1, a_dst1, ss1, sd1);
    scan1<<<NB, 1024, 0, stream>>>(cnt, excl, sums, rpre);
    scan23<<<NB, 1024, 0, stream>>>(excl, sums, rowptr);
    scatter_k<<<(NE / 4 + 255) / 256, 256, 0, stream>>>(ei, rowptr, pos, rpre, col);

    agg_l1<<<(NN * 64 + 255) / 256, 256, 0, stream>>>(rowptr, col, hb, ss1, sd1, b1, P1b);
    gemm_l2<<<(NN + 63) / 64, 256, 0, stream>>>(P1b, Bt2, hb, a_src2, a_dst2, ss2, sd2);
    agg_l2<<<(NN * 64 + 255) / 256, 256, 0, stream>>>(rowptr, col, hb, ss2, sd2, b2, out);
}